// Round 18
// baseline (216.736 us; speedup 1.0000x reference)
//
#include <hip/hip_runtime.h>

// GCN: 2x GraphConv(norm='both') + leaky_relu + linear classifier.
// Interface (validated R6/R7): x/W/b f32, src/dst int32, out f32.
// R34 = R32 + fblocks restored to 1568. R32/R33 post-mortem: W-in-LDS hit
// its target (VGPR 92->40, cap 8 waves/SIMD) but I HALVED the grid to 784
// blocks = 3136 waves = 12.25/CU — less TLP than R31's 24.5/CU. Occupancy
// collapsed (0.5%), +16.4us. Lesson: raising the occupancy CAP is useless
// unless the grid SUPPLIES the waves; R31 at 92 VGPR was capped ~20/CU
// below its 24.5 supplied -> VGPR was binding; at 40 VGPR the full grid
// fits. This round: 1568 blocks x 4 waves = 6272 waves = 24.5/CU resident
// (was 20 in R31), cap 32 (LDS 17.4KB x 8 = 139KB < 160; VGPR 40 <= 64).
// R30: quarter-split FALSIFIED. R28: braid +6.6. R21: balance +8.5.
// R31: bucket wide -9.4. ~57us/iter harness tax is not ours.

typedef __attribute__((ext_vector_type(8))) short short8;
typedef __attribute__((ext_vector_type(4))) float f32x4;

#define NPB 256      // partition blocks
#define SEG 64       // ints per scanmat thread (256*NPB/1024)
#define BSH 9        // bucket shift (width 512)
#define BW  512      // bucket width; n <= 131072 -> <=256 buckets

__device__ __forceinline__ float b2f(unsigned short u) {
    return __uint_as_float(((unsigned int)u) << 16);
}
__device__ __forceinline__ unsigned short f2b(float f) {
    unsigned int i = __float_as_uint(f);
    unsigned int r = (i + 0x7FFFu + ((i >> 16) & 1u)) >> 16;  // RNE
    return (unsigned short)r;
}

// Accumulate 8 bf16 (one 16B gather) into a[0..7]. Even elems: dw<<16;
// odd: dw&0xFFFF0000 — bit-identical to b2f per element, 2 VALU/elem.
__device__ __forceinline__ void acc8(float* a, short8 f) {
    int4 d = *(int4*)&f;
#pragma unroll
    for (int q = 0; q < 4; q++) {
        unsigned int dw = (unsigned int)((q == 0) ? d.x : (q == 1) ? d.y
                                       : (q == 2) ? d.z : d.w);
        a[2 * q]     += __uint_as_float(dw << 16);
        a[2 * q + 1] += __uint_as_float(dw & 0xFFFF0000u);
    }
}

// K1: per-partition-block LDS histograms by dst-bucket and src-bucket.
__global__ __launch_bounds__(1024) void count_kernel(
    const int* __restrict__ src, const int* __restrict__ dst,
    int* __restrict__ cntD, int* __restrict__ cntS, int e, int chunk) {
    __shared__ int hD[256], hS[256];
    int t = threadIdx.x, pb = blockIdx.x;
    if (t < 256) { hD[t] = 0; hS[t] = 0; }
    __syncthreads();
    int e0 = pb * chunk, e1 = min(e, e0 + chunk);
    for (int i = e0 + 4 * t; i + 3 < e1; i += 4096) {
        int4 d4 = *(const int4*)(dst + i);
        int4 s4 = *(const int4*)(src + i);
        atomicAdd(&hD[d4.x >> BSH], 1);
        atomicAdd(&hD[d4.y >> BSH], 1);
        atomicAdd(&hD[d4.z >> BSH], 1);
        atomicAdd(&hD[d4.w >> BSH], 1);
        atomicAdd(&hS[s4.x >> BSH], 1);
        atomicAdd(&hS[s4.y >> BSH], 1);
        atomicAdd(&hS[s4.z >> BSH], 1);
        atomicAdd(&hS[s4.w >> BSH], 1);
    }
    int tb0 = e0 + ((e1 - e0) & ~3);
    for (int i = tb0 + t; i < e1; i += 1024) {
        atomicAdd(&hD[dst[i] >> BSH], 1);
        atomicAdd(&hS[src[i] >> BSH], 1);
    }
    __syncthreads();
    if (t < 256) {
        cntD[t * NPB + pb] = hD[t];
        cntS[t * NPB + pb] = hS[t];
    }
}

// K2: exclusive scan of two 256*NPB-int arrays (block 0: cntD, block 1: cntS)
__global__ __launch_bounds__(1024) void scanmat_kernel(int* __restrict__ cntD,
                                                       int* __restrict__ cntS) {
    int* a = (blockIdx.x == 0) ? cntD : cntS;
    int4* a4 = (int4*)a;
    __shared__ int s[1024];
    int t = threadIdx.x;
    int4 v[SEG / 4];
    int sum = 0;
#pragma unroll
    for (int j = 0; j < SEG / 4; j++) {
        v[j] = a4[t * (SEG / 4) + j];
        sum += v[j].x + v[j].y + v[j].z + v[j].w;
    }
    s[t] = sum;
    __syncthreads();
    for (int d = 1; d < 1024; d <<= 1) {
        int x = (t >= d) ? s[t - d] : 0;
        __syncthreads();
        s[t] += x;
        __syncthreads();
    }
    int run = s[t] - sum;
#pragma unroll
    for (int j = 0; j < SEG / 4; j++) {
        int p0 = run;
        int p1 = p0 + v[j].x;
        int p2 = p1 + v[j].y;
        int p3 = p2 + v[j].z;
        run = p3 + v[j].w;
        a4[t * (SEG / 4) + j] = make_int4(p0, p1, p2, p3);
    }
}

// K3: partition. ebuf u32 = src<<9 | dstLocal; sbuf u16 = srcLocal.
__global__ __launch_bounds__(1024) void part_kernel(
    const int* __restrict__ src, const int* __restrict__ dst,
    const int* __restrict__ cntD, const int* __restrict__ cntS,
    unsigned int* __restrict__ ebuf, unsigned short* __restrict__ sbuf,
    int e, int chunk) {
    __shared__ int cD[256], cS[256];
    int t = threadIdx.x, pb = blockIdx.x;
    if (t < 256) {
        cD[t] = cntD[t * NPB + pb];
        cS[t] = cntS[t * NPB + pb];
    }
    __syncthreads();
    int e0 = pb * chunk, e1 = min(e, e0 + chunk);
    for (int i = e0 + 4 * t; i + 3 < e1; i += 4096) {
        int4 d4 = *(const int4*)(dst + i);
        int4 s4 = *(const int4*)(src + i);
#pragma unroll
        for (int k = 0; k < 4; k++) {
            int s_ = (k == 0) ? s4.x : (k == 1) ? s4.y : (k == 2) ? s4.z : s4.w;
            int d_ = (k == 0) ? d4.x : (k == 1) ? d4.y : (k == 2) ? d4.z : d4.w;
            int pd = atomicAdd(&cD[d_ >> BSH], 1);
            ebuf[pd] = ((unsigned int)s_ << BSH) | (unsigned int)(d_ & (BW - 1));
            int ps_ = atomicAdd(&cS[s_ >> BSH], 1);
            sbuf[ps_] = (unsigned short)(s_ & (BW - 1));
        }
    }
    int tb0 = e0 + ((e1 - e0) & ~3);
    for (int i = tb0 + t; i < e1; i += 1024) {
        int s_ = src[i], d_ = dst[i];
        int pd = atomicAdd(&cD[d_ >> BSH], 1);
        ebuf[pd] = ((unsigned int)s_ << BSH) | (unsigned int)(d_ & (BW - 1));
        int ps_ = atomicAdd(&cS[s_ >> BSH], 1);
        sbuf[ps_] = (unsigned short)(s_ & (BW - 1));
    }
}

// K4: per-bucket, 1024 threads (R31): edge hist + csr scatter stride 1024;
// scan and per-node work guarded to t<512. in-deg hist -> mult-4-PADDED
// row/lenp/cursors -> csr scatter -> sentinel fill; out-deg hist -> oi.
__global__ __launch_bounds__(1024) void bucket_kernel(
    const unsigned int* __restrict__ ebuf, const unsigned short* __restrict__ sbuf,
    const int* __restrict__ cntD, const int* __restrict__ cntS,
    int* __restrict__ row, int* __restrict__ lenp,
    float* __restrict__ ii, float* __restrict__ oi,
    int* __restrict__ csr, int n, int e) {
    __shared__ int cnt[BW], cur[BW], ocnt[BW], ps[BW];
    int t = threadIdx.x, b = blockIdx.x;
    int v0 = b << BSH;
    int eb0 = cntD[b * NPB], eb1 = cntD[(b + 1) * NPB];
    int sb0 = cntS[b * NPB], sb1 = cntS[(b + 1) * NPB];
    int pbase = ((eb0 + 3) & ~3) + (v0 << 2);
    if (t < BW) { cnt[t] = 0; ocnt[t] = 0; }
    __syncthreads();
    for (int i = eb0 + t; i < eb1; i += 1024)
        atomicAdd(&cnt[ebuf[i] & (BW - 1)], 1);
    for (int i = sb0 + t; i < sb1; i += 1024)
        atomicAdd(&ocnt[sbuf[i]], 1);
    __syncthreads();
    int c = 0, p = 0;
    if (t < BW) {
        c = cnt[t];
        p = (c + 3) & ~3;
        ps[t] = p;
    }
    __syncthreads();
    for (int d = 1; d < BW; d <<= 1) {
        int x = (t >= d && t < BW) ? ps[t - d] : 0;
        __syncthreads();
        if (t < BW) ps[t] += x;
        __syncthreads();
    }
    int pexcl = 0;
    if (t < BW) {
        pexcl = ps[t] - p;
        cur[t] = pexcl;
        int v = v0 + t;
        if (v < n) {
            row[v] = pbase + pexcl;
            lenp[v] = p;
            ii[v] = rsqrtf((float)max(c, 1));
            oi[v] = rsqrtf((float)max(ocnt[t], 1));
        }
    }
    __syncthreads();
    for (int i = eb0 + t; i < eb1; i += 1024) {
        unsigned int pk = ebuf[i];
        int r = atomicAdd(&cur[pk & (BW - 1)], 1);
        csr[pbase + r] = (int)(pk >> BSH);
    }
    // sentinel fill (disjoint slots from scatter; no sync needed)
    if (t < BW && v0 + t < n)
        for (int k = c; k < p; k++) csr[pbase + pexcl + k] = n;
}

// K5: wide grid-stride x -> bf16(x*oi); also zeroes the sentinel rows
// (node n) of xb and h1b.
__global__ __launch_bounds__(256) void xconv_kernel(
    const float4* __restrict__ x4, const float* __restrict__ oi,
    ushort4* __restrict__ xb, ushort4* __restrict__ h1b4, int total4) {
    int idx = blockIdx.x * blockDim.x + threadIdx.x;
    int stride = gridDim.x * blockDim.x;
    for (int i = idx; i < total4; i += stride) {
        float s = oi[i >> 4];
        float4 val = x4[i];
        xb[i] = make_ushort4(f2b(val.x * s), f2b(val.y * s),
                             f2b(val.z * s), f2b(val.w * s));
    }
    if (idx < 16) {  // sentinel row: 16 ushort4 = 64 bf16 zeros each
        xb[total4 + idx] = make_ushort4(0, 0, 0, 0);
        h1b4[total4 + idx] = make_ushort4(0, 0, 0, 0);
    }
}

// Fused layer: each wave owns a 16-node output tile (1 group/wave).
// W-fragments in block-shared LDS (wave 0 stages once) — VGPR 40, cap 8
// waves/SIMD; with 1568 blocks the grid supplies 24.5 waves/CU resident.
// Stage A (agg): two 8-node oct passes; oct o = lane>>3 owns node
// rbase+p*8+o; sublane s = lane&7 owns feats 8s..8s+7. Padded CSR: pure
// 8-edge chunks (2x int4 csr loads + 8 gathers in flight) + <=1 4-chunk;
// sentinel edges gather the zero row. bf16 rows -> wave-private LDS tile.
// Stage B (gemm, layout verified R11): mfma_f32_16x16x32_bf16, bias+leaky.
// !FINAL: bf16 h1 pre-scaled by oi. FINAL: fused 64->2 classifier, f32 out.
template <bool FINAL>
__global__ __launch_bounds__(256, 6) void fused_kernel(
    const short8* __restrict__ featb, const int* __restrict__ row,
    const int* __restrict__ lenp, const int* __restrict__ csr,
    const float* __restrict__ ii, const float* __restrict__ oi,
    const float* __restrict__ W, const float* __restrict__ bias,
    const float* __restrict__ Wc, const float* __restrict__ bcl,
    void* __restrict__ out, int n, int nwaves) {
    __shared__ short8 tile[4][16 * 9];   // 4 waves x (16 rows x 9 short8) = 9216B
    __shared__ short8 wlds[32 * 16];     // W frags: ((nt*2+kk)*4+quad)*16+m15, 8KB
    int lane = threadIdx.x & 63;
    int o = lane >> 3, s = lane & 7;         // agg roles
    int m15 = lane & 15, quad = lane >> 4;   // gemm roles
    short8* tl = tile[threadIdx.x >> 6];
    int wid = blockIdx.x * (blockDim.x >> 6) + (threadIdx.x >> 6);
    int ngroups = (n + 15) >> 4;

    if (threadIdx.x < 64) {
        // wave 0 stages all W fragments for its (quad,m15): 8 x short8
#pragma unroll
        for (int nt = 0; nt < 4; nt++)
#pragma unroll
            for (int kk = 0; kk < 2; kk++) {
                short8 f;
#pragma unroll
                for (int j = 0; j < 8; j++)
                    f[j] = (short)f2b(W[(kk * 32 + quad * 8 + j) * 64 + nt * 16 + m15]);
                wlds[((nt * 2 + kk) * 4 + quad) * 16 + m15] = f;
            }
    }
    __syncthreads();

    float bias_r[4];
#pragma unroll
    for (int nt = 0; nt < 4; nt++) bias_r[nt] = bias[nt * 16 + m15];

    float wc_r[4][2];
    float bc0 = 0.f, bc1 = 0.f;
    if constexpr (FINAL) {
#pragma unroll
        for (int nt = 0; nt < 4; nt++) {
            wc_r[nt][0] = Wc[(nt * 16 + m15) * 2];
            wc_r[nt][1] = Wc[(nt * 16 + m15) * 2 + 1];
        }
        bc0 = bcl[0];
        bc1 = bcl[1];
    }

    for (int g = wid; g < ngroups; g += nwaves) {
        int rbase = g << 4;

        // ---- Stage A: aggregate 16 nodes (two oct passes) ----
#pragma unroll
        for (int p = 0; p < 2; p++) {
            int v = rbase + p * 8 + o;
            bool valid = v < n;
            int base = 0, pc = 0;
            if (valid) { base = row[v]; pc = lenp[v]; }
            float a[8];
#pragma unroll
            for (int k = 0; k < 8; k++) a[k] = 0.f;
            int j = 0;
            for (; j + 7 < pc; j += 8) {
                int4 u0 = *(const int4*)(csr + base + j);
                int4 u1 = *(const int4*)(csr + base + j + 4);
                short8 f0 = featb[(size_t)u0.x * 8 + s];
                short8 f1 = featb[(size_t)u0.y * 8 + s];
                short8 f2 = featb[(size_t)u0.z * 8 + s];
                short8 f3 = featb[(size_t)u0.w * 8 + s];
                short8 f4 = featb[(size_t)u1.x * 8 + s];
                short8 f5 = featb[(size_t)u1.y * 8 + s];
                short8 f6 = featb[(size_t)u1.z * 8 + s];
                short8 f7 = featb[(size_t)u1.w * 8 + s];
                acc8(a, f0); acc8(a, f1); acc8(a, f2); acc8(a, f3);
                acc8(a, f4); acc8(a, f5); acc8(a, f6); acc8(a, f7);
            }
            if (j < pc) {  // exactly 4 remain (pc % 4 == 0)
                int4 u0 = *(const int4*)(csr + base + j);
                short8 f0 = featb[(size_t)u0.x * 8 + s];
                short8 f1 = featb[(size_t)u0.y * 8 + s];
                short8 f2 = featb[(size_t)u0.z * 8 + s];
                short8 f3 = featb[(size_t)u0.w * 8 + s];
                acc8(a, f0); acc8(a, f1); acc8(a, f2); acc8(a, f3);
            }
            float iiv = valid ? ii[v] : 0.f;
            short8 r;
#pragma unroll
            for (int m = 0; m < 8; m++) r[m] = (short)f2b(a[m] * iiv);
            tl[(p * 8 + o) * 9 + s] = r;   // row p*8+o, feats 8s..8s+7
        }

        // ---- Stage B: 16x64 @ 64x64 via MFMA (W frags from LDS) ----
        short8 af0 = tl[m15 * 9 + quad];       // k = quad*8 .. quad*8+7
        short8 af1 = tl[m15 * 9 + 4 + quad];   // k = 32 + quad*8 ..

        f32x4 acc[4];
#pragma unroll
        for (int nt = 0; nt < 4; nt++) {
            short8 b0 = wlds[((nt * 2 + 0) * 4 + quad) * 16 + m15];
            short8 b1 = wlds[((nt * 2 + 1) * 4 + quad) * 16 + m15];
            f32x4 z = {0.f, 0.f, 0.f, 0.f};
            z = __builtin_amdgcn_mfma_f32_16x16x32_bf16(af0, b0, z, 0, 0, 0);
            z = __builtin_amdgcn_mfma_f32_16x16x32_bf16(af1, b1, z, 0, 0, 0);
            acc[nt] = z;
        }

        if constexpr (!FINAL) {
#pragma unroll
            for (int r = 0; r < 4; r++) {
                int vr = rbase + quad * 4 + r;
                float os = (vr < n) ? oi[vr] : 0.f;
#pragma unroll
                for (int nt = 0; nt < 4; nt++) {
                    float ov = acc[nt][r] + bias_r[nt];
                    ov = (ov > 0.f) ? ov : 0.01f * ov;
                    if (vr < n)
                        ((unsigned short*)out)[(size_t)vr * 64 + nt * 16 + m15] = f2b(ov * os);
                }
            }
        } else {
#pragma unroll
            for (int r = 0; r < 4; r++) {
                float p0 = 0.f, p1 = 0.f;
#pragma unroll
                for (int nt = 0; nt < 4; nt++) {
                    float ov = acc[nt][r] + bias_r[nt];
                    ov = (ov > 0.f) ? ov : 0.01f * ov;
                    p0 = fmaf(ov, wc_r[nt][0], p0);
                    p1 = fmaf(ov, wc_r[nt][1], p1);
                }
#pragma unroll
                for (int off = 1; off < 16; off <<= 1) {
                    p0 += __shfl_xor(p0, off);
                    p1 += __shfl_xor(p1, off);
                }
                int vr = rbase + quad * 4 + r;
                if (m15 == 0 && vr < n)
                    ((float2*)out)[vr] = make_float2(p0 + bc0, p1 + bc1);
            }
        }
    }
}

extern "C" void kernel_launch(void* const* d_in, const int* in_sizes, int n_in,
                              void* d_out, int out_size, void* d_ws, size_t ws_size,
                              hipStream_t stream) {
    const float* x  = (const float*)d_in[0];
    const int* src  = (const int*)d_in[1];
    const int* dst  = (const int*)d_in[2];
    const float* W1 = (const float*)d_in[3];
    const float* b1 = (const float*)d_in[4];
    const float* W2 = (const float*)d_in[5];
    const float* b2 = (const float*)d_in[6];
    const float* Wc = (const float*)d_in[7];
    const float* bc = (const float*)d_in[8];
    int n = in_sizes[0] / 64;
    int e = in_sizes[1];
    int total = n * 64;
    int nbuck = (n + BW - 1) >> BSH;

    char* ws = (char*)d_ws;
    size_t off = 0;
    auto take = [&](size_t bytes) -> char* {
        char* p = ws + off;
        off = (off + bytes + 255) & ~(size_t)255;
        return p;
    };
    int* cntD = (int*)take(256 * NPB * 4);
    int* cntS = (int*)take(256 * NPB * 4);
    unsigned int* ebuf = (unsigned int*)take((size_t)e * 4);     // 4 MB
    unsigned short* sbuf = (unsigned short*)take((size_t)e * 2); // 2 MB
    int* row  = (int*)take((size_t)(n + 1) * 4);
    int* lenp = (int*)take((size_t)n * 4);
    int* csr  = (int*)take(((size_t)e + 4 * (size_t)nbuck * BW + 16) * 4); // mult-4 padded
    float* oi = (float*)take((size_t)n * 4);
    float* ii = (float*)take((size_t)n * 4);
    unsigned short* xb  = (unsigned short*)take((size_t)(total + 64) * 2);  // +sentinel row
    unsigned short* h1b = (unsigned short*)take((size_t)(total + 64) * 2);  // +sentinel row

    // chunk multiple of 4 so int4 lanes stay 16B-aligned per block.
    int chunk = (((e + NPB - 1) / NPB) + 3) & ~3;

    count_kernel<<<NPB, 1024, 0, stream>>>(src, dst, cntD, cntS, e, chunk);
    scanmat_kernel<<<2, 1024, 0, stream>>>(cntD, cntS);
    part_kernel<<<NPB, 1024, 0, stream>>>(src, dst, cntD, cntS, ebuf, sbuf, e, chunk);
    bucket_kernel<<<nbuck, 1024, 0, stream>>>(ebuf, sbuf, cntD, cntS,
                                              row, lenp, ii, oi, csr, n, e);
    xconv_kernel<<<2048, 256, 0, stream>>>((const float4*)x, oi, (ushort4*)xb,
                                           (ushort4*)h1b, n * 16);

    // 1568 blocks * 4 waves = 6272 waves = 24.5/CU resident (cap 32 at
    // 40 VGPR + 17.4KB LDS); ngroups = 6250 -> 1 group/wave.
    const int fblocks = 1568;
    const int fwaves = fblocks * (256 / 64);

    fused_kernel<false><<<fblocks, 256, 0, stream>>>((const short8*)xb, row, lenp, csr,
                                                     ii, oi, W1, b1, nullptr, nullptr,
                                                     h1b, n, fwaves);
    fused_kernel<true><<<fblocks, 256, 0, stream>>>((const short8*)h1b, row, lenp, csr,
                                                    ii, nullptr, W2, b2, Wc, bc,
                                                    d_out, n, fwaves);
}

// Round 19
// 186.987 us; speedup vs baseline: 1.1591x; 1.1591x over previous
//
#include <hip/hip_runtime.h>

// GCN: 2x GraphConv(norm='both') + leaky_relu + linear classifier.
// Interface (validated R6/R7): x/W/b f32, src/dst int32, out f32.
// R35 = EXACT REVERT to R31 (best measured: 187.35us).
// R34 post-mortem closed the occupancy question: W-in-LDS got VGPR 40 /
// occ 44%, but FETCH rose 50->79.6MB (L2 thrash from bigger instantaneous
// random working set) + 50K LDS bank conflicts; fused stayed ~45.5us. The
// gather sits on a latency<->thrash seesaw; R31's 92-VGPR ~20 waves/CU
// config is the measured balance point. Falsified ledger: R21 balance
// +8.5, R28 braid +6.6, R30 quarter-split +30.8, R32/R34 occupancy +16/+29.
// If this reproduces ~187, next round states the structural ceiling.
// ~57us/iter harness tax (poison fill + d_in restore) is not ours.

typedef __attribute__((ext_vector_type(8))) short short8;
typedef __attribute__((ext_vector_type(4))) float f32x4;

#define NPB 256      // partition blocks
#define SEG 64       // ints per scanmat thread (256*NPB/1024)
#define BSH 9        // bucket shift (width 512)
#define BW  512      // bucket width; n <= 131072 -> <=256 buckets

__device__ __forceinline__ float b2f(unsigned short u) {
    return __uint_as_float(((unsigned int)u) << 16);
}
__device__ __forceinline__ unsigned short f2b(float f) {
    unsigned int i = __float_as_uint(f);
    unsigned int r = (i + 0x7FFFu + ((i >> 16) & 1u)) >> 16;  // RNE
    return (unsigned short)r;
}

// Accumulate 8 bf16 (one 16B gather) into a[0..7]. Even elems: dw<<16;
// odd: dw&0xFFFF0000 — bit-identical to b2f per element, 2 VALU/elem.
__device__ __forceinline__ void acc8(float* a, short8 f) {
    int4 d = *(int4*)&f;
#pragma unroll
    for (int q = 0; q < 4; q++) {
        unsigned int dw = (unsigned int)((q == 0) ? d.x : (q == 1) ? d.y
                                       : (q == 2) ? d.z : d.w);
        a[2 * q]     += __uint_as_float(dw << 16);
        a[2 * q + 1] += __uint_as_float(dw & 0xFFFF0000u);
    }
}

// K1: per-partition-block LDS histograms by dst-bucket and src-bucket.
__global__ __launch_bounds__(1024) void count_kernel(
    const int* __restrict__ src, const int* __restrict__ dst,
    int* __restrict__ cntD, int* __restrict__ cntS, int e, int chunk) {
    __shared__ int hD[256], hS[256];
    int t = threadIdx.x, pb = blockIdx.x;
    if (t < 256) { hD[t] = 0; hS[t] = 0; }
    __syncthreads();
    int e0 = pb * chunk, e1 = min(e, e0 + chunk);
    for (int i = e0 + 4 * t; i + 3 < e1; i += 4096) {
        int4 d4 = *(const int4*)(dst + i);
        int4 s4 = *(const int4*)(src + i);
        atomicAdd(&hD[d4.x >> BSH], 1);
        atomicAdd(&hD[d4.y >> BSH], 1);
        atomicAdd(&hD[d4.z >> BSH], 1);
        atomicAdd(&hD[d4.w >> BSH], 1);
        atomicAdd(&hS[s4.x >> BSH], 1);
        atomicAdd(&hS[s4.y >> BSH], 1);
        atomicAdd(&hS[s4.z >> BSH], 1);
        atomicAdd(&hS[s4.w >> BSH], 1);
    }
    int tb0 = e0 + ((e1 - e0) & ~3);
    for (int i = tb0 + t; i < e1; i += 1024) {
        atomicAdd(&hD[dst[i] >> BSH], 1);
        atomicAdd(&hS[src[i] >> BSH], 1);
    }
    __syncthreads();
    if (t < 256) {
        cntD[t * NPB + pb] = hD[t];
        cntS[t * NPB + pb] = hS[t];
    }
}

// K2: exclusive scan of two 256*NPB-int arrays (block 0: cntD, block 1: cntS)
__global__ __launch_bounds__(1024) void scanmat_kernel(int* __restrict__ cntD,
                                                       int* __restrict__ cntS) {
    int* a = (blockIdx.x == 0) ? cntD : cntS;
    int4* a4 = (int4*)a;
    __shared__ int s[1024];
    int t = threadIdx.x;
    int4 v[SEG / 4];
    int sum = 0;
#pragma unroll
    for (int j = 0; j < SEG / 4; j++) {
        v[j] = a4[t * (SEG / 4) + j];
        sum += v[j].x + v[j].y + v[j].z + v[j].w;
    }
    s[t] = sum;
    __syncthreads();
    for (int d = 1; d < 1024; d <<= 1) {
        int x = (t >= d) ? s[t - d] : 0;
        __syncthreads();
        s[t] += x;
        __syncthreads();
    }
    int run = s[t] - sum;
#pragma unroll
    for (int j = 0; j < SEG / 4; j++) {
        int p0 = run;
        int p1 = p0 + v[j].x;
        int p2 = p1 + v[j].y;
        int p3 = p2 + v[j].z;
        run = p3 + v[j].w;
        a4[t * (SEG / 4) + j] = make_int4(p0, p1, p2, p3);
    }
}

// K3: partition. ebuf u32 = src<<9 | dstLocal; sbuf u16 = srcLocal.
__global__ __launch_bounds__(1024) void part_kernel(
    const int* __restrict__ src, const int* __restrict__ dst,
    const int* __restrict__ cntD, const int* __restrict__ cntS,
    unsigned int* __restrict__ ebuf, unsigned short* __restrict__ sbuf,
    int e, int chunk) {
    __shared__ int cD[256], cS[256];
    int t = threadIdx.x, pb = blockIdx.x;
    if (t < 256) {
        cD[t] = cntD[t * NPB + pb];
        cS[t] = cntS[t * NPB + pb];
    }
    __syncthreads();
    int e0 = pb * chunk, e1 = min(e, e0 + chunk);
    for (int i = e0 + 4 * t; i + 3 < e1; i += 4096) {
        int4 d4 = *(const int4*)(dst + i);
        int4 s4 = *(const int4*)(src + i);
#pragma unroll
        for (int k = 0; k < 4; k++) {
            int s_ = (k == 0) ? s4.x : (k == 1) ? s4.y : (k == 2) ? s4.z : s4.w;
            int d_ = (k == 0) ? d4.x : (k == 1) ? d4.y : (k == 2) ? d4.z : d4.w;
            int pd = atomicAdd(&cD[d_ >> BSH], 1);
            ebuf[pd] = ((unsigned int)s_ << BSH) | (unsigned int)(d_ & (BW - 1));
            int ps_ = atomicAdd(&cS[s_ >> BSH], 1);
            sbuf[ps_] = (unsigned short)(s_ & (BW - 1));
        }
    }
    int tb0 = e0 + ((e1 - e0) & ~3);
    for (int i = tb0 + t; i < e1; i += 1024) {
        int s_ = src[i], d_ = dst[i];
        int pd = atomicAdd(&cD[d_ >> BSH], 1);
        ebuf[pd] = ((unsigned int)s_ << BSH) | (unsigned int)(d_ & (BW - 1));
        int ps_ = atomicAdd(&cS[s_ >> BSH], 1);
        sbuf[ps_] = (unsigned short)(s_ & (BW - 1));
    }
}

// K4: per-bucket, 1024 threads: edge hist + csr scatter stride 1024; scan
// and per-node work guarded to t<512. in-deg hist -> mult-4-PADDED
// row/lenp/cursors -> csr scatter -> sentinel fill; out-deg hist -> oi.
__global__ __launch_bounds__(1024) void bucket_kernel(
    const unsigned int* __restrict__ ebuf, const unsigned short* __restrict__ sbuf,
    const int* __restrict__ cntD, const int* __restrict__ cntS,
    int* __restrict__ row, int* __restrict__ lenp,
    float* __restrict__ ii, float* __restrict__ oi,
    int* __restrict__ csr, int n, int e) {
    __shared__ int cnt[BW], cur[BW], ocnt[BW], ps[BW];
    int t = threadIdx.x, b = blockIdx.x;
    int v0 = b << BSH;
    int eb0 = cntD[b * NPB], eb1 = cntD[(b + 1) * NPB];
    int sb0 = cntS[b * NPB], sb1 = cntS[(b + 1) * NPB];
    int pbase = ((eb0 + 3) & ~3) + (v0 << 2);
    if (t < BW) { cnt[t] = 0; ocnt[t] = 0; }
    __syncthreads();
    for (int i = eb0 + t; i < eb1; i += 1024)
        atomicAdd(&cnt[ebuf[i] & (BW - 1)], 1);
    for (int i = sb0 + t; i < sb1; i += 1024)
        atomicAdd(&ocnt[sbuf[i]], 1);
    __syncthreads();
    int c = 0, p = 0;
    if (t < BW) {
        c = cnt[t];
        p = (c + 3) & ~3;
        ps[t] = p;
    }
    __syncthreads();
    for (int d = 1; d < BW; d <<= 1) {
        int x = (t >= d && t < BW) ? ps[t - d] : 0;
        __syncthreads();
        if (t < BW) ps[t] += x;
        __syncthreads();
    }
    int pexcl = 0;
    if (t < BW) {
        pexcl = ps[t] - p;
        cur[t] = pexcl;
        int v = v0 + t;
        if (v < n) {
            row[v] = pbase + pexcl;
            lenp[v] = p;
            ii[v] = rsqrtf((float)max(c, 1));
            oi[v] = rsqrtf((float)max(ocnt[t], 1));
        }
    }
    __syncthreads();
    for (int i = eb0 + t; i < eb1; i += 1024) {
        unsigned int pk = ebuf[i];
        int r = atomicAdd(&cur[pk & (BW - 1)], 1);
        csr[pbase + r] = (int)(pk >> BSH);
    }
    // sentinel fill (disjoint slots from scatter; no sync needed)
    if (t < BW && v0 + t < n)
        for (int k = c; k < p; k++) csr[pbase + pexcl + k] = n;
}

// K5: wide grid-stride x -> bf16(x*oi); also zeroes the sentinel rows
// (node n) of xb and h1b.
__global__ __launch_bounds__(256) void xconv_kernel(
    const float4* __restrict__ x4, const float* __restrict__ oi,
    ushort4* __restrict__ xb, ushort4* __restrict__ h1b4, int total4) {
    int idx = blockIdx.x * blockDim.x + threadIdx.x;
    int stride = gridDim.x * blockDim.x;
    for (int i = idx; i < total4; i += stride) {
        float s = oi[i >> 4];
        float4 val = x4[i];
        xb[i] = make_ushort4(f2b(val.x * s), f2b(val.y * s),
                             f2b(val.z * s), f2b(val.w * s));
    }
    if (idx < 16) {  // sentinel row: 16 ushort4 = 64 bf16 zeros each
        xb[total4 + idx] = make_ushort4(0, 0, 0, 0);
        h1b4[total4 + idx] = make_ushort4(0, 0, 0, 0);
    }
}

// Fused layer: each wave owns a 16-node output tile.
// Stage A (agg): two 8-node oct passes; oct o = lane>>3 owns node
// rbase+p*8+o; sublane s = lane&7 owns feats 8s..8s+7. Padded CSR: pure
// 8-edge chunks (2x int4 csr loads + 8 gathers in flight) + <=1 4-chunk;
// sentinel edges gather the zero row (L1-hot, +0.0 after real edges ->
// rounding unchanged). bf16 rows -> wave-private LDS tile (144B rows).
// Stage B (gemm, layout verified R11): mfma_f32_16x16x32_bf16, bias+leaky.
// !FINAL: bf16 h1 pre-scaled by oi. FINAL: fused 64->2 classifier, f32 out.
template <bool FINAL>
__global__ __launch_bounds__(256) void fused_kernel(
    const short8* __restrict__ featb, const int* __restrict__ row,
    const int* __restrict__ lenp, const int* __restrict__ csr,
    const float* __restrict__ ii, const float* __restrict__ oi,
    const float* __restrict__ W, const float* __restrict__ bias,
    const float* __restrict__ Wc, const float* __restrict__ bcl,
    void* __restrict__ out, int n, int nwaves) {
    __shared__ short8 tile[4][16 * 9];   // 4 waves x (16 rows x 9 short8) = 9216B
    int lane = threadIdx.x & 63;
    int o = lane >> 3, s = lane & 7;         // agg roles
    int m15 = lane & 15, quad = lane >> 4;   // gemm roles
    short8* tl = tile[threadIdx.x >> 6];
    int wid = blockIdx.x * (blockDim.x >> 6) + (threadIdx.x >> 6);
    int ngroups = (n + 15) >> 4;

    short8 bf[4][2];
#pragma unroll
    for (int nt = 0; nt < 4; nt++)
#pragma unroll
        for (int kk = 0; kk < 2; kk++)
#pragma unroll
            for (int j = 0; j < 8; j++)
                bf[nt][kk][j] = (short)f2b(W[(kk * 32 + quad * 8 + j) * 64 + nt * 16 + m15]);

    float bias_r[4];
#pragma unroll
    for (int nt = 0; nt < 4; nt++) bias_r[nt] = bias[nt * 16 + m15];

    float wc_r[4][2];
    float bc0 = 0.f, bc1 = 0.f;
    if constexpr (FINAL) {
#pragma unroll
        for (int nt = 0; nt < 4; nt++) {
            wc_r[nt][0] = Wc[(nt * 16 + m15) * 2];
            wc_r[nt][1] = Wc[(nt * 16 + m15) * 2 + 1];
        }
        bc0 = bcl[0];
        bc1 = bcl[1];
    }

    for (int g = wid; g < ngroups; g += nwaves) {
        int rbase = g << 4;

        // ---- Stage A: aggregate 16 nodes (two oct passes) ----
#pragma unroll
        for (int p = 0; p < 2; p++) {
            int v = rbase + p * 8 + o;
            bool valid = v < n;
            int base = 0, pc = 0;
            if (valid) { base = row[v]; pc = lenp[v]; }
            float a[8];
#pragma unroll
            for (int k = 0; k < 8; k++) a[k] = 0.f;
            int j = 0;
            for (; j + 7 < pc; j += 8) {
                int4 u0 = *(const int4*)(csr + base + j);
                int4 u1 = *(const int4*)(csr + base + j + 4);
                short8 f0 = featb[(size_t)u0.x * 8 + s];
                short8 f1 = featb[(size_t)u0.y * 8 + s];
                short8 f2 = featb[(size_t)u0.z * 8 + s];
                short8 f3 = featb[(size_t)u0.w * 8 + s];
                short8 f4 = featb[(size_t)u1.x * 8 + s];
                short8 f5 = featb[(size_t)u1.y * 8 + s];
                short8 f6 = featb[(size_t)u1.z * 8 + s];
                short8 f7 = featb[(size_t)u1.w * 8 + s];
                acc8(a, f0); acc8(a, f1); acc8(a, f2); acc8(a, f3);
                acc8(a, f4); acc8(a, f5); acc8(a, f6); acc8(a, f7);
            }
            if (j < pc) {  // exactly 4 remain (pc % 4 == 0)
                int4 u0 = *(const int4*)(csr + base + j);
                short8 f0 = featb[(size_t)u0.x * 8 + s];
                short8 f1 = featb[(size_t)u0.y * 8 + s];
                short8 f2 = featb[(size_t)u0.z * 8 + s];
                short8 f3 = featb[(size_t)u0.w * 8 + s];
                acc8(a, f0); acc8(a, f1); acc8(a, f2); acc8(a, f3);
            }
            float iiv = valid ? ii[v] : 0.f;
            short8 r;
#pragma unroll
            for (int m = 0; m < 8; m++) r[m] = (short)f2b(a[m] * iiv);
            tl[(p * 8 + o) * 9 + s] = r;   // row p*8+o, feats 8s..8s+7
        }

        // ---- Stage B: 16x64 @ 64x64 via MFMA ----
        short8 af0 = tl[m15 * 9 + quad];       // k = quad*8 .. quad*8+7
        short8 af1 = tl[m15 * 9 + 4 + quad];   // k = 32 + quad*8 ..

        f32x4 acc[4];
#pragma unroll
        for (int nt = 0; nt < 4; nt++) {
            f32x4 z = {0.f, 0.f, 0.f, 0.f};
            z = __builtin_amdgcn_mfma_f32_16x16x32_bf16(af0, bf[nt][0], z, 0, 0, 0);
            z = __builtin_amdgcn_mfma_f32_16x16x32_bf16(af1, bf[nt][1], z, 0, 0, 0);
            acc[nt] = z;
        }

        if constexpr (!FINAL) {
#pragma unroll
            for (int r = 0; r < 4; r++) {
                int vr = rbase + quad * 4 + r;
                float os = (vr < n) ? oi[vr] : 0.f;
#pragma unroll
                for (int nt = 0; nt < 4; nt++) {
                    float ov = acc[nt][r] + bias_r[nt];
                    ov = (ov > 0.f) ? ov : 0.01f * ov;
                    if (vr < n)
                        ((unsigned short*)out)[(size_t)vr * 64 + nt * 16 + m15] = f2b(ov * os);
                }
            }
        } else {
#pragma unroll
            for (int r = 0; r < 4; r++) {
                float p0 = 0.f, p1 = 0.f;
#pragma unroll
                for (int nt = 0; nt < 4; nt++) {
                    float ov = acc[nt][r] + bias_r[nt];
                    ov = (ov > 0.f) ? ov : 0.01f * ov;
                    p0 = fmaf(ov, wc_r[nt][0], p0);
                    p1 = fmaf(ov, wc_r[nt][1], p1);
                }
#pragma unroll
                for (int off = 1; off < 16; off <<= 1) {
                    p0 += __shfl_xor(p0, off);
                    p1 += __shfl_xor(p1, off);
                }
                int vr = rbase + quad * 4 + r;
                if (m15 == 0 && vr < n)
                    ((float2*)out)[vr] = make_float2(p0 + bc0, p1 + bc1);
            }
        }
    }
}

extern "C" void kernel_launch(void* const* d_in, const int* in_sizes, int n_in,
                              void* d_out, int out_size, void* d_ws, size_t ws_size,
                              hipStream_t stream) {
    const float* x  = (const float*)d_in[0];
    const int* src  = (const int*)d_in[1];
    const int* dst  = (const int*)d_in[2];
    const float* W1 = (const float*)d_in[3];
    const float* b1 = (const float*)d_in[4];
    const float* W2 = (const float*)d_in[5];
    const float* b2 = (const float*)d_in[6];
    const float* Wc = (const float*)d_in[7];
    const float* bc = (const float*)d_in[8];
    int n = in_sizes[0] / 64;
    int e = in_sizes[1];
    int total = n * 64;
    int nbuck = (n + BW - 1) >> BSH;

    char* ws = (char*)d_ws;
    size_t off = 0;
    auto take = [&](size_t bytes) -> char* {
        char* p = ws + off;
        off = (off + bytes + 255) & ~(size_t)255;
        return p;
    };
    int* cntD = (int*)take(256 * NPB * 4);
    int* cntS = (int*)take(256 * NPB * 4);
    unsigned int* ebuf = (unsigned int*)take((size_t)e * 4);     // 4 MB
    unsigned short* sbuf = (unsigned short*)take((size_t)e * 2); // 2 MB
    int* row  = (int*)take((size_t)(n + 1) * 4);
    int* lenp = (int*)take((size_t)n * 4);
    int* csr  = (int*)take(((size_t)e + 4 * (size_t)nbuck * BW + 16) * 4); // mult-4 padded
    float* oi = (float*)take((size_t)n * 4);
    float* ii = (float*)take((size_t)n * 4);
    unsigned short* xb  = (unsigned short*)take((size_t)(total + 64) * 2);  // +sentinel row
    unsigned short* h1b = (unsigned short*)take((size_t)(total + 64) * 2);  // +sentinel row

    // chunk multiple of 4 so int4 lanes stay 16B-aligned per block.
    int chunk = (((e + NPB - 1) / NPB) + 3) & ~3;

    count_kernel<<<NPB, 1024, 0, stream>>>(src, dst, cntD, cntS, e, chunk);
    scanmat_kernel<<<2, 1024, 0, stream>>>(cntD, cntS);
    part_kernel<<<NPB, 1024, 0, stream>>>(src, dst, cntD, cntS, ebuf, sbuf, e, chunk);
    bucket_kernel<<<nbuck, 1024, 0, stream>>>(ebuf, sbuf, cntD, cntS,
                                              row, lenp, ii, oi, csr, n, e);
    xconv_kernel<<<2048, 256, 0, stream>>>((const float4*)x, oi, (ushort4*)xb,
                                           (ushort4*)h1b, n * 16);

    // 1568 blocks * 4 waves = 6272 waves; ngroups = 6250 -> 1 group/wave.
    const int fblocks = 1568;
    const int fwaves = fblocks * (256 / 64);

    fused_kernel<false><<<fblocks, 256, 0, stream>>>((const short8*)xb, row, lenp, csr,
                                                     ii, oi, W1, b1, nullptr, nullptr,
                                                     h1b, n, fwaves);
    fused_kernel<true><<<fblocks, 256, 0, stream>>>((const short8*)h1b, row, lenp, csr,
                                                    ii, nullptr, W2, b2, Wc, bc,
                                                    d_out, n, fwaves);
}